// Round 4
// baseline (523.213 us; speedup 1.0000x reference)
//
#include <hip/hip_runtime.h>
#include <stdint.h>

#define EMB 768
#define SEQ 2048
#define BATCH 4
#define NHEADS 12
#define HDIM 64
#define FFDIM 3072
#define NTOK (BATCH*SEQ)
#define LNEPS 1e-5f
#define QSCALE 0.1803368801111137f  /* 0.125 * log2(e) */

typedef __attribute__((ext_vector_type(8))) short bf16x8;
typedef __attribute__((ext_vector_type(4))) float f32x4;

__device__ __forceinline__ uint16_t f2bf(float f){
  union { float f; uint32_t u; } v; v.f = f;
  uint32_t r = v.u + 0x7fffu + ((v.u >> 16) & 1u);
  return (uint16_t)(r >> 16);
}
// pack two floats to bf16 pair, round-half-up (add 0x8000, take hi16) via v_perm
__device__ __forceinline__ uint32_t pk_rhu(float lo, float hi){
  union { float f; uint32_t u; } a, b; a.f = lo; b.f = hi;
  return __builtin_amdgcn_perm(b.u + 0x8000u, a.u + 0x8000u, 0x07060302u);
}

// async global->LDS, 16B per lane. LDS dest = wave-uniform base + lane*16.
typedef __attribute__((address_space(3))) uint32_t lds32_t;
typedef __attribute__((address_space(1))) const uint32_t glb32_t;
__device__ __forceinline__ void gload16(const void* g, void* l){
  __builtin_amdgcn_global_load_lds((glb32_t*)(uintptr_t)g,
                                   (lds32_t*)(uintptr_t)l, 16, 0, 0);
}

// ---------- merged fp32 [K,N] -> bf16 [N,K] weight convert+transpose ----------
struct TPtrs { const float* src[6]; uint16_t* dst[6]; };
__global__ __launch_bounds__(256) void transpose_all(TPtrs tp){
  int idx = blockIdx.x;
  int which, bx, by, K, N;
  if (idx < 2304){ which = idx/576; int l = idx - which*576; bx = l%24; by = l/24; K = 768;  N = 768;  }
  else if (idx < 4608){ which = 4; int l = idx-2304; bx = l%96; by = l/96; K = 768;  N = 3072; }
  else { which = 5; int l = idx-4608; bx = l%24; by = l/24; K = 3072; N = 768;  }
  const float* w = tp.src[which];
  uint16_t* wt   = tp.dst[which];
  __shared__ uint16_t tile[32][33];
  int n0 = bx*32, k0 = by*32;
  #pragma unroll
  for (int i=0;i<4;i++){
    int k = threadIdx.y + i*8;
    tile[k][threadIdx.x] = f2bf(w[(size_t)(k0+k)*N + n0 + threadIdx.x]);
  }
  __syncthreads();
  #pragma unroll
  for (int i=0;i<4;i++){
    int n = threadIdx.y + i*8;
    wt[(size_t)(n0+n)*K + k0 + threadIdx.x] = tile[threadIdx.x][n];
  }
}

// ---------- LayerNorm: fp32 in -> bf16 out, one wave per row ----------
__global__ __launch_bounds__(256) void ln_kernel(const float* __restrict__ x,
    const float* __restrict__ sc, const float* __restrict__ sh,
    uint16_t* __restrict__ out)
{
  int row = blockIdx.x*4 + (threadIdx.x>>6);
  int ln = threadIdx.x & 63;
  const float4* xr = (const float4*)(x + (size_t)row*EMB);
  float4 v0 = xr[ln], v1 = xr[64+ln], v2 = xr[128+ln];
  float s  = v0.x+v0.y+v0.z+v0.w + v1.x+v1.y+v1.z+v1.w + v2.x+v2.y+v2.z+v2.w;
  float s2 = v0.x*v0.x+v0.y*v0.y+v0.z*v0.z+v0.w*v0.w
           + v1.x*v1.x+v1.y*v1.y+v1.z*v1.z+v1.w*v1.w
           + v2.x*v2.x+v2.y*v2.y+v2.z*v2.z+v2.w*v2.w;
  #pragma unroll
  for (int off=1;off<64;off<<=1){ s += __shfl_xor(s,off); s2 += __shfl_xor(s2,off); }
  float mean = s*(1.f/768.f);
  float var  = s2*(1.f/768.f) - mean*mean;
  float rstd = rsqrtf(var + LNEPS);
  uint16_t* orow = out + (size_t)row*EMB;
  float4 vv[3] = {v0,v1,v2};
  #pragma unroll
  for (int i=0;i<3;i++){
    int c = (i*64+ln)*4;
    ushort4 o4;
    o4.x = f2bf((vv[i].x-mean)*rstd*sc[c+0] + sh[c+0]);
    o4.y = f2bf((vv[i].y-mean)*rstd*sc[c+1] + sh[c+1]);
    o4.z = f2bf((vv[i].z-mean)*rstd*sc[c+2] + sh[c+2]);
    o4.w = f2bf((vv[i].w-mean)*rstd*sc[c+3] + sh[c+3]);
    *(ushort4*)(orow + c) = o4;
  }
}

// ---------- GEMM: C[M,N] = A[M,K](bf16) * Bt[N,K](bf16)^T, tile 128x128x32 ----------
// MODE 0: store bf16 (z==0 Q scaled by QSCALE; z==2 -> V transposed [b][h][d][s])
// MODE 1: +bias +fp32 residual -> fp32
// MODE 2: +bias, gelu -> bf16
// MODE 3: +bias +fp32 residual -> fp32 (final out)
template<int MODE>
__global__ __launch_bounds__(256) void gemm_bt(const uint16_t* __restrict__ A,
    const uint16_t* __restrict__ Bt0,
    const float* __restrict__ bias,
    const float* __restrict__ resid,
    void* __restrict__ outp,
    uint16_t* __restrict__ vt_out,
    int N, int K, long bt_zstride, long out_zstride)
{
  __shared__ __align__(16) uint16_t As[128][32];
  __shared__ __align__(16) uint16_t Bs[128][32];
  const uint16_t* Bt = Bt0 + (size_t)blockIdx.z * bt_zstride;
  int tid = threadIdx.x;
  int wave = tid>>6, ln = tid&63, lane16 = ln&15, quad = ln>>4;
  int m0 = blockIdx.x*128, n0 = blockIdx.y*128;
  int wm = (wave>>1)*64, wn = (wave&1)*64;
  f32x4 zf = {0.f,0.f,0.f,0.f};
  f32x4 acc[4][4];
  #pragma unroll
  for (int i=0;i<4;i++)
    #pragma unroll
    for (int j=0;j<4;j++) acc[i][j]=zf;
  int ar = tid>>2;
  int ac = (tid&3)*8;
  const uint16_t* Arow0 = A  + (size_t)(m0+ar)*K    + ac;
  const uint16_t* Arow1 = A  + (size_t)(m0+ar+64)*K + ac;
  const uint16_t* Brow0 = Bt + (size_t)(n0+ar)*K    + ac;
  const uint16_t* Brow1 = Bt + (size_t)(n0+ar+64)*K + ac;
  char* lA = (char*)&As[0][0] + wave*1024;
  char* lB = (char*)&Bs[0][0] + wave*1024;
  for (int k0=0;k0<K;k0+=32){
    __syncthreads();
    gload16(Arow0 + k0, lA);
    gload16(Arow1 + k0, lA + 4096);
    gload16(Brow0 + k0, lB);
    gload16(Brow1 + k0, lB + 4096);
    __syncthreads();
    bf16x8 af[4], bfr[4];
    #pragma unroll
    for (int mi=0;mi<4;mi++) af[mi]  = *(const bf16x8*)&As[wm+mi*16+lane16][quad*8];
    #pragma unroll
    for (int ni=0;ni<4;ni++) bfr[ni] = *(const bf16x8*)&Bs[wn+ni*16+lane16][quad*8];
    #pragma unroll
    for (int mi=0;mi<4;mi++)
      #pragma unroll
      for (int ni=0;ni<4;ni++)
        acc[mi][ni] = __builtin_amdgcn_mfma_f32_16x16x32_bf16(af[mi], bfr[ni], acc[mi][ni], 0,0,0);
  }
  if (MODE==0 && blockIdx.z==2){
    #pragma unroll
    for (int mi=0;mi<4;mi++){
      int mrow0 = m0 + wm + mi*16 + quad*4;
      int bb = mrow0 >> 11, s = mrow0 & 2047;
      #pragma unroll
      for (int ni=0;ni<4;ni++){
        int ncol = n0 + wn + ni*16 + lane16;
        int hh = ncol >> 6, dd = ncol & 63;
        ushort4 o4 = { f2bf(acc[mi][ni][0]), f2bf(acc[mi][ni][1]),
                       f2bf(acc[mi][ni][2]), f2bf(acc[mi][ni][3]) };
        *(ushort4*)(vt_out + ((size_t)((bb*NHEADS+hh)*HDIM + dd))*SEQ + s) = o4;
      }
    }
    return;
  }
  float oscale = (MODE==0 && blockIdx.z==0) ? QSCALE : 1.0f;
  #pragma unroll
  for (int mi=0;mi<4;mi++){
    #pragma unroll
    for (int r=0;r<4;r++){
      int mrow = m0 + wm + mi*16 + quad*4 + r;
      #pragma unroll
      for (int ni=0;ni<4;ni++){
        int ncol = n0 + wn + ni*16 + lane16;
        float vv = acc[mi][ni][r];
        size_t idx = (size_t)mrow*N + ncol;
        if (MODE==0){
          ((uint16_t*)outp)[(size_t)blockIdx.z*out_zstride + idx] = f2bf(vv*oscale);
        } else if (MODE==1){
          ((float*)outp)[idx] = vv + bias[ncol] + resid[idx];
        } else if (MODE==2){
          float t = vv + bias[ncol];
          float u = 1.5957691216057308f*(t + 0.044715f*t*t*t);
          ((uint16_t*)outp)[idx] = f2bf(t / (1.f + __expf(-u)));
        } else {
          ((float*)outp)[idx] = vv + bias[ncol] + resid[idx];
        }
      }
    }
  }
}

// ---------- Flash attention v2: no LDS, no barriers, balanced waves ----------
// grid (SEQ/64 = 32, NHEADS, BATCH), block 256.
// Block covers q-32-tiles {x, 63-x}; wave w owns one independent 16-row band.
// S^T = K*Q^T (Q pre-scaled by 0.125*log2e); softmax in exp2 domain over 64-kv
// chunks; P^T -> PV B-frags via 16 bpermutes; O^T = V^T*P^T with V^T from global.
__global__ __launch_bounds__(256, 4) void attn_kernel(const uint16_t* __restrict__ q,
    const uint16_t* __restrict__ k, const uint16_t* __restrict__ vt,
    uint16_t* __restrict__ ctx)
{
  const f32x4 zf = {0.f,0.f,0.f,0.f};
  int tid = threadIdx.x;
  int wave = tid>>6, ln = tid&63, l16 = ln&15, quad = ln>>4;
  int b = blockIdx.z, h = blockIdx.y;
  int tile = (wave < 2) ? blockIdx.x : (63 - blockIdx.x);
  int q0w = tile*32 + (wave&1)*16;
  // Q as B-fragment: n=q=l16, k=d=quad*8+j (+32 second half)
  const uint16_t* qrow = q + ((size_t)(b*SEQ + q0w + l16))*EMB + h*HDIM + quad*8;
  bf16x8 qf0 = *(const bf16x8*)(qrow);
  bf16x8 qf1 = *(const bf16x8*)(qrow + 32);
  // K fragment base: row kv0 + f*16 + l16, col h*HDIM + half*32 + quad*8
  const uint16_t* kbase = k + ((size_t)(b*SEQ + l16))*EMB + h*HDIM + quad*8;
  // V^T fragment base: row d = t*16 + l16, col kv0 + g*32 + quad*8
  const uint16_t* vbase = vt + ((size_t)((b*NHEADS + h)*HDIM + l16))*SEQ + quad*8;
  f32x4 o[4]; o[0]=zf; o[1]=zf; o[2]=zf; o[3]=zf;
  float m_l = -3.0e38f, l_l = 0.f;
  int myq = q0w + l16;

  auto step = [&](int kv0, bool masked){
    // ---- load K frags (8) and V^T frags (8) ----
    bf16x8 kf[4][2], vf[2][4];
    #pragma unroll
    for (int f=0; f<4; f++){
      const uint16_t* kr = kbase + (size_t)(kv0 + f*16)*EMB;
      kf[f][0] = *(const bf16x8*)(kr);
      kf[f][1] = *(const bf16x8*)(kr + 32);
    }
    #pragma unroll
    for (int t=0; t<4; t++){
      const uint16_t* vr = vbase + (size_t)(t*16)*SEQ + kv0;
      vf[0][t] = *(const bf16x8*)(vr);
      vf[1][t] = *(const bf16x8*)(vr + 32);
    }
    // ---- S^T = K * Q^T : 4 frags of 16kv x 16q ----
    f32x4 st[4];
    #pragma unroll
    for (int f=0; f<4; f++){
      st[f] = __builtin_amdgcn_mfma_f32_16x16x32_bf16(kf[f][0], qf0, zf, 0,0,0);
      st[f] = __builtin_amdgcn_mfma_f32_16x16x32_bf16(kf[f][1], qf1, st[f], 0,0,0);
    }
    // ---- causal mask (boundary tile only) ----
    if (masked){
      #pragma unroll
      for (int f=0; f<4; f++){
        int kvf = kv0 + f*16 + quad*4;
        #pragma unroll
        for (int r=0; r<4; r++)
          if (kvf + r > myq) st[f][r] = -1e30f;
      }
    }
    // ---- online softmax over 16 values/lane (exp2 domain) ----
    float cmax = -1e30f;
    #pragma unroll
    for (int f=0; f<4; f++)
      #pragma unroll
      for (int r=0; r<4; r++) cmax = fmaxf(cmax, st[f][r]);
    cmax = fmaxf(cmax, __shfl_xor(cmax,16));
    cmax = fmaxf(cmax, __shfl_xor(cmax,32));
    float mn = fmaxf(m_l, cmax);
    float alpha = __builtin_amdgcn_exp2f(m_l - mn);
    float rs = 0.f;
    #pragma unroll
    for (int f=0; f<4; f++)
      #pragma unroll
      for (int r=0; r<4; r++){
        st[f][r] = __builtin_amdgcn_exp2f(st[f][r] - mn);
        rs += st[f][r];
      }
    rs += __shfl_xor(rs,16); rs += __shfl_xor(rs,32);
    l_l = l_l*alpha + rs; m_l = mn;
    #pragma unroll
    for (int t=0; t<4; t++)
      #pragma unroll
      for (int r=0; r<4; r++) o[t][r] *= alpha;
    // ---- P^T (C layout) -> 2 PV B-frags via bpermute ----
    uint32_t dw[4][2];
    #pragma unroll
    for (int f=0; f<4; f++){
      dw[f][0] = pk_rhu(st[f][0], st[f][1]);
      dw[f][1] = pk_rhu(st[f][2], st[f][3]);
    }
    union { uint32_t u[4]; bf16x8 v; } pb[2];
    #pragma unroll
    for (int g=0; g<2; g++)
      #pragma unroll
      for (int j=0; j<4; j++){
        int src = 16*(2*(quad&1) + (j>>1)) + l16;
        uint32_t lo = (uint32_t)__shfl((int)dw[2*g  ][j&1], src, 64);
        uint32_t hi = (uint32_t)__shfl((int)dw[2*g+1][j&1], src, 64);
        pb[g].u[j] = (quad>>1) ? hi : lo;
      }
    // ---- O^T += V^T * P^T ----
    #pragma unroll
    for (int t=0; t<4; t++){
      o[t] = __builtin_amdgcn_mfma_f32_16x16x32_bf16(vf[0][t], pb[0].v, o[t], 0,0,0);
      o[t] = __builtin_amdgcn_mfma_f32_16x16x32_bf16(vf[1][t], pb[1].v, o[t], 0,0,0);
    }
  };

  int nfull = q0w >> 6;
  for (int i=0; i<nfull; i++) step(i*64, false);
  step(nfull*64, true);

  float inv = 1.0f / l_l;
  uint16_t* crow = ctx + ((size_t)(b*SEQ + q0w + l16))*EMB + h*HDIM + quad*4;
  #pragma unroll
  for (int t=0; t<4; t++){
    ushort4 w4 = { f2bf(o[t][0]*inv), f2bf(o[t][1]*inv),
                   f2bf(o[t][2]*inv), f2bf(o[t][3]*inv) };
    *(ushort4*)(crow + t*16) = w4;
  }
}

extern "C" void kernel_launch(void* const* d_in, const int* in_sizes, int n_in,
                              void* d_out, int out_size, void* d_ws, size_t ws_size,
                              hipStream_t stream) {
  const float* x     = (const float*)d_in[0];
  const float* ln1_s = (const float*)d_in[1];
  const float* ln1_b = (const float*)d_in[2];
  const float* wq    = (const float*)d_in[3];
  const float* wk    = (const float*)d_in[4];
  const float* wv    = (const float*)d_in[5];
  const float* wo    = (const float*)d_in[6];
  const float* bo    = (const float*)d_in[7];
  const float* ln2_s = (const float*)d_in[8];
  const float* ln2_b = (const float*)d_in[9];
  const float* w1    = (const float*)d_in[10];
  const float* b1    = (const float*)d_in[11];
  const float* w2    = (const float*)d_in[12];
  const float* b2    = (const float*)d_in[13];

  uint16_t* wqkv_t = (uint16_t*)d_ws;                 // 3 x [768][768]
  uint16_t* wo_t   = wqkv_t + 3*EMB*EMB;              // [768][768]
  uint16_t* w1_t   = wo_t   + EMB*EMB;                // [3072][768]
  uint16_t* w2_t   = w1_t   + (size_t)FFDIM*EMB;      // [768][3072]
  uint16_t* xn     = w2_t   + (size_t)EMB*FFDIM;      // [8192][768]
  uint16_t* qkv    = xn     + (size_t)NTOK*EMB;       // q,k normal; v slot unused
  uint16_t* ctx    = qkv    + (size_t)3*NTOK*EMB;     // [8192][768]
  uint16_t* hff    = qkv;                             // [8192][3072] overlays qkv+ctx
  float*    x1     = (float*)(ctx + (size_t)NTOK*EMB);// [8192][768] fp32
  uint16_t* vt     = (uint16_t*)(x1 + (size_t)NTOK*EMB); // [4][12][64][2048] V^T

  TPtrs tp;
  tp.src[0]=wq; tp.src[1]=wk; tp.src[2]=wv; tp.src[3]=wo; tp.src[4]=w1; tp.src[5]=w2;
  tp.dst[0]=wqkv_t; tp.dst[1]=wqkv_t+EMB*EMB; tp.dst[2]=wqkv_t+2*EMB*EMB;
  tp.dst[3]=wo_t; tp.dst[4]=w1_t; tp.dst[5]=w2_t;
  transpose_all<<<6912, dim3(32,8), 0, stream>>>(tp);

  ln_kernel<<<NTOK/4, 256, 0, stream>>>(x, ln1_s, ln1_b, xn);
  gemm_bt<0><<<dim3(NTOK/128, EMB/128, 3), 256, 0, stream>>>(
      xn, wqkv_t, nullptr, nullptr, qkv, vt, EMB, EMB,
      (long)EMB*EMB, (long)NTOK*EMB);
  attn_kernel<<<dim3(SEQ/64, NHEADS, BATCH), 256, 0, stream>>>(
      qkv, qkv + (size_t)NTOK*EMB, vt, ctx);
  gemm_bt<1><<<dim3(NTOK/128, EMB/128, 1), 256, 0, stream>>>(
      ctx, wo_t, bo, x, x1, nullptr, EMB, EMB, 0, 0);
  ln_kernel<<<NTOK/4, 256, 0, stream>>>(x1, ln2_s, ln2_b, xn);
  gemm_bt<2><<<dim3(NTOK/128, FFDIM/128, 1), 256, 0, stream>>>(
      xn, w1_t, b1, nullptr, hff, nullptr, FFDIM, EMB, 0, 0);
  gemm_bt<3><<<dim3(NTOK/128, EMB/128, 1), 256, 0, stream>>>(
      hff, w2_t, b2, x1, d_out, nullptr, EMB, FFDIM, 0, 0);
}

// Round 5
// 414.552 us; speedup vs baseline: 1.2621x; 1.2621x over previous
//
#include <hip/hip_runtime.h>
#include <stdint.h>

#define EMB 768
#define SEQ 2048
#define BATCH 4
#define NHEADS 12
#define HDIM 64
#define FFDIM 3072
#define NTOK (BATCH*SEQ)
#define LNEPS 1e-5f
#define QSCALE 0.1803368801111137f  /* 0.125 * log2(e) */

typedef __attribute__((ext_vector_type(8))) short bf16x8;
typedef __attribute__((ext_vector_type(4))) float f32x4;

__device__ __forceinline__ uint16_t f2bf(float f){
  union { float f; uint32_t u; } v; v.f = f;
  uint32_t r = v.u + 0x7fffu + ((v.u >> 16) & 1u);
  return (uint16_t)(r >> 16);
}
// pack two floats to bf16 pair, round-half-up (add 0x8000, take hi16) via v_perm
__device__ __forceinline__ uint32_t pk_rhu(float lo, float hi){
  union { float f; uint32_t u; } a, b; a.f = lo; b.f = hi;
  return __builtin_amdgcn_perm(b.u + 0x8000u, a.u + 0x8000u, 0x07060302u);
}

// async global->LDS, 16B per lane. LDS dest = wave-uniform base + lane*16.
typedef __attribute__((address_space(3))) uint32_t lds32_t;
typedef __attribute__((address_space(1))) const uint32_t glb32_t;
__device__ __forceinline__ void gload16(const void* g, void* l){
  __builtin_amdgcn_global_load_lds((glb32_t*)(uintptr_t)g,
                                   (lds32_t*)(uintptr_t)l, 16, 0, 0);
}

// ---------- merged fp32 [K,N] -> bf16 [N,K] weight convert+transpose ----------
struct TPtrs { const float* src[6]; uint16_t* dst[6]; };
__global__ __launch_bounds__(256) void transpose_all(TPtrs tp){
  int idx = blockIdx.x;
  int which, bx, by, K, N;
  if (idx < 2304){ which = idx/576; int l = idx - which*576; bx = l%24; by = l/24; K = 768;  N = 768;  }
  else if (idx < 4608){ which = 4; int l = idx-2304; bx = l%96; by = l/96; K = 768;  N = 3072; }
  else { which = 5; int l = idx-4608; bx = l%24; by = l/24; K = 3072; N = 768;  }
  const float* w = tp.src[which];
  uint16_t* wt   = tp.dst[which];
  __shared__ uint16_t tile[32][33];
  int n0 = bx*32, k0 = by*32;
  #pragma unroll
  for (int i=0;i<4;i++){
    int k = threadIdx.y + i*8;
    tile[k][threadIdx.x] = f2bf(w[(size_t)(k0+k)*N + n0 + threadIdx.x]);
  }
  __syncthreads();
  #pragma unroll
  for (int i=0;i<4;i++){
    int n = threadIdx.y + i*8;
    wt[(size_t)(n0+n)*K + k0 + threadIdx.x] = tile[threadIdx.x][n];
  }
}

// ---------- LayerNorm: fp32 in -> bf16 out, one wave per row ----------
__global__ __launch_bounds__(256) void ln_kernel(const float* __restrict__ x,
    const float* __restrict__ sc, const float* __restrict__ sh,
    uint16_t* __restrict__ out)
{
  int row = blockIdx.x*4 + (threadIdx.x>>6);
  int ln = threadIdx.x & 63;
  const float4* xr = (const float4*)(x + (size_t)row*EMB);
  float4 v0 = xr[ln], v1 = xr[64+ln], v2 = xr[128+ln];
  float s  = v0.x+v0.y+v0.z+v0.w + v1.x+v1.y+v1.z+v1.w + v2.x+v2.y+v2.z+v2.w;
  float s2 = v0.x*v0.x+v0.y*v0.y+v0.z*v0.z+v0.w*v0.w
           + v1.x*v1.x+v1.y*v1.y+v1.z*v1.z+v1.w*v1.w
           + v2.x*v2.x+v2.y*v2.y+v2.z*v2.z+v2.w*v2.w;
  #pragma unroll
  for (int off=1;off<64;off<<=1){ s += __shfl_xor(s,off); s2 += __shfl_xor(s2,off); }
  float mean = s*(1.f/768.f);
  float var  = s2*(1.f/768.f) - mean*mean;
  float rstd = rsqrtf(var + LNEPS);
  uint16_t* orow = out + (size_t)row*EMB;
  float4 vv[3] = {v0,v1,v2};
  #pragma unroll
  for (int i=0;i<3;i++){
    int c = (i*64+ln)*4;
    ushort4 o4;
    o4.x = f2bf((vv[i].x-mean)*rstd*sc[c+0] + sh[c+0]);
    o4.y = f2bf((vv[i].y-mean)*rstd*sc[c+1] + sh[c+1]);
    o4.z = f2bf((vv[i].z-mean)*rstd*sc[c+2] + sh[c+2]);
    o4.w = f2bf((vv[i].w-mean)*rstd*sc[c+3] + sh[c+3]);
    *(ushort4*)(orow + c) = o4;
  }
}

// ---------- GEMM: C[M,N] = A[M,K](bf16) * Bt[N,K](bf16)^T, tile 128x128x32 ----------
// MODE 0: store bf16 (z==0 Q scaled by QSCALE; z==2 -> V transposed [b][h][d][s])
// MODE 1: +bias +fp32 residual -> fp32
// MODE 2: +bias, gelu -> bf16
// MODE 3: +bias +fp32 residual -> fp32 (final out)
template<int MODE>
__global__ __launch_bounds__(256) void gemm_bt(const uint16_t* __restrict__ A,
    const uint16_t* __restrict__ Bt0,
    const float* __restrict__ bias,
    const float* __restrict__ resid,
    void* __restrict__ outp,
    uint16_t* __restrict__ vt_out,
    int N, int K, long bt_zstride, long out_zstride)
{
  __shared__ __align__(16) uint16_t As[128][32];
  __shared__ __align__(16) uint16_t Bs[128][32];
  const uint16_t* Bt = Bt0 + (size_t)blockIdx.z * bt_zstride;
  int tid = threadIdx.x;
  int wave = tid>>6, ln = tid&63, lane16 = ln&15, quad = ln>>4;
  int m0 = blockIdx.x*128, n0 = blockIdx.y*128;
  int wm = (wave>>1)*64, wn = (wave&1)*64;
  f32x4 zf = {0.f,0.f,0.f,0.f};
  f32x4 acc[4][4];
  #pragma unroll
  for (int i=0;i<4;i++)
    #pragma unroll
    for (int j=0;j<4;j++) acc[i][j]=zf;
  int ar = tid>>2;
  int ac = (tid&3)*8;
  const uint16_t* Arow0 = A  + (size_t)(m0+ar)*K    + ac;
  const uint16_t* Arow1 = A  + (size_t)(m0+ar+64)*K + ac;
  const uint16_t* Brow0 = Bt + (size_t)(n0+ar)*K    + ac;
  const uint16_t* Brow1 = Bt + (size_t)(n0+ar+64)*K + ac;
  char* lA = (char*)&As[0][0] + wave*1024;
  char* lB = (char*)&Bs[0][0] + wave*1024;
  for (int k0=0;k0<K;k0+=32){
    __syncthreads();
    gload16(Arow0 + k0, lA);
    gload16(Arow1 + k0, lA + 4096);
    gload16(Brow0 + k0, lB);
    gload16(Brow1 + k0, lB + 4096);
    __syncthreads();
    bf16x8 af[4], bfr[4];
    #pragma unroll
    for (int mi=0;mi<4;mi++) af[mi]  = *(const bf16x8*)&As[wm+mi*16+lane16][quad*8];
    #pragma unroll
    for (int ni=0;ni<4;ni++) bfr[ni] = *(const bf16x8*)&Bs[wn+ni*16+lane16][quad*8];
    #pragma unroll
    for (int mi=0;mi<4;mi++)
      #pragma unroll
      for (int ni=0;ni<4;ni++)
        acc[mi][ni] = __builtin_amdgcn_mfma_f32_16x16x32_bf16(af[mi], bfr[ni], acc[mi][ni], 0,0,0);
  }
  if (MODE==0 && blockIdx.z==2){
    #pragma unroll
    for (int mi=0;mi<4;mi++){
      int mrow0 = m0 + wm + mi*16 + quad*4;
      int bb = mrow0 >> 11, s = mrow0 & 2047;
      #pragma unroll
      for (int ni=0;ni<4;ni++){
        int ncol = n0 + wn + ni*16 + lane16;
        int hh = ncol >> 6, dd = ncol & 63;
        ushort4 o4 = { f2bf(acc[mi][ni][0]), f2bf(acc[mi][ni][1]),
                       f2bf(acc[mi][ni][2]), f2bf(acc[mi][ni][3]) };
        *(ushort4*)(vt_out + ((size_t)((bb*NHEADS+hh)*HDIM + dd))*SEQ + s) = o4;
      }
    }
    return;
  }
  float oscale = (MODE==0 && blockIdx.z==0) ? QSCALE : 1.0f;
  #pragma unroll
  for (int mi=0;mi<4;mi++){
    #pragma unroll
    for (int r=0;r<4;r++){
      int mrow = m0 + wm + mi*16 + quad*4 + r;
      #pragma unroll
      for (int ni=0;ni<4;ni++){
        int ncol = n0 + wn + ni*16 + lane16;
        float vv = acc[mi][ni][r];
        size_t idx = (size_t)mrow*N + ncol;
        if (MODE==0){
          ((uint16_t*)outp)[(size_t)blockIdx.z*out_zstride + idx] = f2bf(vv*oscale);
        } else if (MODE==1){
          ((float*)outp)[idx] = vv + bias[ncol] + resid[idx];
        } else if (MODE==2){
          float t = vv + bias[ncol];
          float u = 1.5957691216057308f*(t + 0.044715f*t*t*t);
          ((uint16_t*)outp)[idx] = f2bf(t / (1.f + __expf(-u)));
        } else {
          ((float*)outp)[idx] = vv + bias[ncol] + resid[idx];
        }
      }
    }
  }
}

// ---------- Flash attention v3: LDS-shared K/V, async double-buffer, balanced ----------
// grid (16, NHEADS, BATCH), block 256 (4 waves, 16 q-rows each).
// Block processes 64-q tiles {p, 31-p} sequentially -> 33 kv-steps for every block.
// LDS layout column-block-major: Ks[buf][c][kv][8] (c = 16B d-block) so that
// global_load_lds lane-ordered writes == conflict-free b128 fragment reads.
__global__ __launch_bounds__(256, 3) void attn_kernel(const uint16_t* __restrict__ q,
    const uint16_t* __restrict__ k, const uint16_t* __restrict__ vt,
    uint16_t* __restrict__ ctx)
{
  __shared__ __align__(16) uint16_t Ks[2][8][64][8];  // [buf][d-blk][kv][8]
  __shared__ __align__(16) uint16_t Vs[2][8][64][8];  // [buf][kv-blk][d][8]
  const f32x4 zf = {0.f,0.f,0.f,0.f};
  int tid = threadIdx.x;
  int wave = tid>>6, ln = tid&63, l16 = ln&15, quad = ln>>4;
  int b = blockIdx.z, h = blockIdx.y;
  int p = blockIdx.x;
  size_t kgbase = ((size_t)(b*SEQ + ln))*EMB + h*HDIM;       // + kv0*EMB + c*8
  size_t vgbase = ((size_t)((b*NHEADS + h)*HDIM + ln))*SEQ;  // + kv0 + c*8

  f32x4 o[4];
  float m_l, l_l;
  bf16x8 qf0, qf1;
  int q0w, myq;

  auto stage = [&](int buf, int kv0){
    #pragma unroll
    for (int i=0;i<2;i++){
      int c = wave + 4*i;
      gload16(k  + kgbase + (size_t)kv0*EMB + c*8, &Ks[buf][c][0][0]);
      gload16(vt + vgbase + kv0 + c*8,             &Vs[buf][c][0][0]);
    }
  };
  auto init_tile = [&](int tile){
    q0w = tile*64 + wave*16;
    myq = q0w + l16;
    const uint16_t* qrow = q + ((size_t)(b*SEQ + q0w + l16))*EMB + h*HDIM + quad*8;
    qf0 = *(const bf16x8*)(qrow);
    qf1 = *(const bf16x8*)(qrow + 32);
    o[0]=zf; o[1]=zf; o[2]=zf; o[3]=zf;
    m_l = -3.0e38f; l_l = 0.f;
  };
  auto writeout = [&](){
    float inv = 1.0f / l_l;
    uint16_t* crow = ctx + ((size_t)(b*SEQ + q0w + l16))*EMB + h*HDIM + quad*4;
    #pragma unroll
    for (int t=0; t<4; t++){
      ushort4 w4 = { f2bf(o[t][0]*inv), f2bf(o[t][1]*inv),
                     f2bf(o[t][2]*inv), f2bf(o[t][3]*inv) };
      *(ushort4*)(crow + t*16) = w4;
    }
  };
  auto compute = [&](int buf, int kv0, bool masked){
    bf16x8 kf[4][2], vf[2][4];
    #pragma unroll
    for (int f=0; f<4; f++){
      kf[f][0] = *(const bf16x8*)&Ks[buf][quad  ][f*16+l16][0];
      kf[f][1] = *(const bf16x8*)&Ks[buf][quad+4][f*16+l16][0];
    }
    #pragma unroll
    for (int t=0; t<4; t++){
      vf[0][t] = *(const bf16x8*)&Vs[buf][quad  ][t*16+l16][0];
      vf[1][t] = *(const bf16x8*)&Vs[buf][quad+4][t*16+l16][0];
    }
    f32x4 st[4];
    #pragma unroll
    for (int f=0; f<4; f++){
      st[f] = __builtin_amdgcn_mfma_f32_16x16x32_bf16(kf[f][0], qf0, zf, 0,0,0);
      st[f] = __builtin_amdgcn_mfma_f32_16x16x32_bf16(kf[f][1], qf1, st[f], 0,0,0);
    }
    if (masked){
      #pragma unroll
      for (int f=0; f<4; f++){
        int kvf = kv0 + f*16 + quad*4;
        #pragma unroll
        for (int r=0; r<4; r++)
          if (kvf + r > myq) st[f][r] = -1e30f;
      }
    }
    float cmax = -1e30f;
    #pragma unroll
    for (int f=0; f<4; f++)
      #pragma unroll
      for (int r=0; r<4; r++) cmax = fmaxf(cmax, st[f][r]);
    cmax = fmaxf(cmax, __shfl_xor(cmax,16));
    cmax = fmaxf(cmax, __shfl_xor(cmax,32));
    float mn = fmaxf(m_l, cmax);
    float alpha = __builtin_amdgcn_exp2f(m_l - mn);
    float rs = 0.f;
    #pragma unroll
    for (int f=0; f<4; f++)
      #pragma unroll
      for (int r=0; r<4; r++){
        st[f][r] = __builtin_amdgcn_exp2f(st[f][r] - mn);
        rs += st[f][r];
      }
    rs += __shfl_xor(rs,16); rs += __shfl_xor(rs,32);
    l_l = l_l*alpha + rs; m_l = mn;
    #pragma unroll
    for (int t=0; t<4; t++)
      #pragma unroll
      for (int r=0; r<4; r++) o[t][r] *= alpha;
    uint32_t dw[4][2];
    #pragma unroll
    for (int f=0; f<4; f++){
      dw[f][0] = pk_rhu(st[f][0], st[f][1]);
      dw[f][1] = pk_rhu(st[f][2], st[f][3]);
    }
    union { uint32_t u[4]; bf16x8 v; } pb[2];
    #pragma unroll
    for (int g=0; g<2; g++)
      #pragma unroll
      for (int j=0; j<4; j++){
        int src = 16*(2*(quad&1) + (j>>1)) + l16;
        uint32_t lo = (uint32_t)__shfl((int)dw[2*g  ][j&1], src, 64);
        uint32_t hi = (uint32_t)__shfl((int)dw[2*g+1][j&1], src, 64);
        pb[g].u[j] = (quad>>1) ? hi : lo;
      }
    #pragma unroll
    for (int t=0; t<4; t++){
      o[t] = __builtin_amdgcn_mfma_f32_16x16x32_bf16(vf[0][t], pb[0].v, o[t], 0,0,0);
      o[t] = __builtin_amdgcn_mfma_f32_16x16x32_bf16(vf[1][t], pb[1].v, o[t], 0,0,0);
    }
  };

  int n0 = p + 1, ntot = 33;
  init_tile(p);
  stage(0, 0);
  for (int s=0; s<ntot; s++){
    int sl = (s < n0) ? s : s - n0;
    int kv0 = sl*64;
    __syncthreads();                 // drains staging of buf s&1
    if (s+1 < ntot){
      int sn = s+1;
      int snl = (sn < n0) ? sn : sn - n0;
      stage(sn&1, snl*64);           // in flight during compute below
    }
    if (s == n0){ writeout(); init_tile(31 - p); }
    bool masked = (s == n0-1) || (s == ntot-1);
    compute(s&1, kv0, masked);
  }
  writeout();
}

extern "C" void kernel_launch(void* const* d_in, const int* in_sizes, int n_in,
                              void* d_out, int out_size, void* d_ws, size_t ws_size,
                              hipStream_t stream) {
  const float* x     = (const float*)d_in[0];
  const float* ln1_s = (const float*)d_in[1];
  const float* ln1_b = (const float*)d_in[2];
  const float* wq    = (const float*)d_in[3];
  const float* wk    = (const float*)d_in[4];
  const float* wv    = (const float*)d_in[5];
  const float* wo    = (const float*)d_in[6];
  const float* bo    = (const float*)d_in[7];
  const float* ln2_s = (const float*)d_in[8];
  const float* ln2_b = (const float*)d_in[9];
  const float* w1    = (const float*)d_in[10];
  const float* b1    = (const float*)d_in[11];
  const float* w2    = (const float*)d_in[12];
  const float* b2    = (const float*)d_in[13];

  uint16_t* wqkv_t = (uint16_t*)d_ws;                 // 3 x [768][768]
  uint16_t* wo_t   = wqkv_t + 3*EMB*EMB;              // [768][768]
  uint16_t* w1_t   = wo_t   + EMB*EMB;                // [3072][768]
  uint16_t* w2_t   = w1_t   + (size_t)FFDIM*EMB;      // [768][3072]
  uint16_t* xn     = w2_t   + (size_t)EMB*FFDIM;      // [8192][768]
  uint16_t* qkv    = xn     + (size_t)NTOK*EMB;       // q,k normal; v slot unused
  uint16_t* ctx    = qkv    + (size_t)3*NTOK*EMB;     // [8192][768]
  uint16_t* hff    = qkv;                             // [8192][3072] overlays qkv+ctx
  float*    x1     = (float*)(ctx + (size_t)NTOK*EMB);// [8192][768] fp32
  uint16_t* vt     = (uint16_t*)(x1 + (size_t)NTOK*EMB); // [4][12][64][2048] V^T

  TPtrs tp;
  tp.src[0]=wq; tp.src[1]=wk; tp.src[2]=wv; tp.src[3]=wo; tp.src[4]=w1; tp.src[5]=w2;
  tp.dst[0]=wqkv_t; tp.dst[1]=wqkv_t+EMB*EMB; tp.dst[2]=wqkv_t+2*EMB*EMB;
  tp.dst[3]=wo_t; tp.dst[4]=w1_t; tp.dst[5]=w2_t;
  transpose_all<<<6912, dim3(32,8), 0, stream>>>(tp);

  ln_kernel<<<NTOK/4, 256, 0, stream>>>(x, ln1_s, ln1_b, xn);
  gemm_bt<0><<<dim3(NTOK/128, EMB/128, 3), 256, 0, stream>>>(
      xn, wqkv_t, nullptr, nullptr, qkv, vt, EMB, EMB,
      (long)EMB*EMB, (long)NTOK*EMB);
  attn_kernel<<<dim3(16, NHEADS, BATCH), 256, 0, stream>>>(
      qkv, qkv + (size_t)NTOK*EMB, vt, ctx);
  gemm_bt<1><<<dim3(NTOK/128, EMB/128, 1), 256, 0, stream>>>(
      ctx, wo_t, bo, x, x1, nullptr, EMB, EMB, 0, 0);
  ln_kernel<<<NTOK/4, 256, 0, stream>>>(x1, ln2_s, ln2_b, xn);
  gemm_bt<2><<<dim3(NTOK/128, FFDIM/128, 1), 256, 0, stream>>>(
      xn, w1_t, b1, nullptr, hff, nullptr, FFDIM, EMB, 0, 0);
  gemm_bt<3><<<dim3(NTOK/128, EMB/128, 1), 256, 0, stream>>>(
      hff, w2_t, b2, x1, d_out, nullptr, EMB, FFDIM, 0, 0);
}

// Round 6
// 380.854 us; speedup vs baseline: 1.3738x; 1.0885x over previous
//
#include <hip/hip_runtime.h>
#include <stdint.h>

#define EMB 768
#define SEQ 2048
#define BATCH 4
#define NHEADS 12
#define HDIM 64
#define FFDIM 3072
#define NTOK (BATCH*SEQ)
#define LNEPS 1e-5f
#define QSCALE 0.1803368801111137f  /* 0.125 * log2(e) */

typedef __attribute__((ext_vector_type(8))) short bf16x8;
typedef __attribute__((ext_vector_type(4))) float f32x4;

__device__ __forceinline__ uint16_t f2bf(float f){
  union { float f; uint32_t u; } v; v.f = f;
  uint32_t r = v.u + 0x7fffu + ((v.u >> 16) & 1u);
  return (uint16_t)(r >> 16);
}
// pack two floats to bf16 pair, round-half-up (add 0x8000, take hi16) via v_perm
__device__ __forceinline__ uint32_t pk_rhu(float lo, float hi){
  union { float f; uint32_t u; } a, b; a.f = lo; b.f = hi;
  return __builtin_amdgcn_perm(b.u + 0x8000u, a.u + 0x8000u, 0x07060302u);
}

// async global->LDS, 16B per lane. LDS dest = wave-uniform base + lane*16.
typedef __attribute__((address_space(3))) uint32_t lds32_t;
typedef __attribute__((address_space(1))) const uint32_t glb32_t;
__device__ __forceinline__ void gload16(const void* g, void* l){
  __builtin_amdgcn_global_load_lds((glb32_t*)(uintptr_t)g,
                                   (lds32_t*)(uintptr_t)l, 16, 0, 0);
}

// ---------- merged fp32 [K,N] -> bf16 [N,K] weight convert+transpose ----------
struct TPtrs { const float* src[6]; uint16_t* dst[6]; };
__global__ __launch_bounds__(256) void transpose_all(TPtrs tp){
  int idx = blockIdx.x;
  int which, bx, by, K, N;
  if (idx < 2304){ which = idx/576; int l = idx - which*576; bx = l%24; by = l/24; K = 768;  N = 768;  }
  else if (idx < 4608){ which = 4; int l = idx-2304; bx = l%96; by = l/96; K = 768;  N = 3072; }
  else { which = 5; int l = idx-4608; bx = l%24; by = l/24; K = 3072; N = 768;  }
  const float* w = tp.src[which];
  uint16_t* wt   = tp.dst[which];
  __shared__ uint16_t tile[32][33];
  int n0 = bx*32, k0 = by*32;
  #pragma unroll
  for (int i=0;i<4;i++){
    int k = threadIdx.y + i*8;
    tile[k][threadIdx.x] = f2bf(w[(size_t)(k0+k)*N + n0 + threadIdx.x]);
  }
  __syncthreads();
  #pragma unroll
  for (int i=0;i<4;i++){
    int n = threadIdx.y + i*8;
    wt[(size_t)(n0+n)*K + k0 + threadIdx.x] = tile[threadIdx.x][n];
  }
}

// ---------- LayerNorm: fp32 in -> bf16 out, one wave per row ----------
__global__ __launch_bounds__(256) void ln_kernel(const float* __restrict__ x,
    const float* __restrict__ sc, const float* __restrict__ sh,
    uint16_t* __restrict__ out)
{
  int row = blockIdx.x*4 + (threadIdx.x>>6);
  int ln = threadIdx.x & 63;
  const float4* xr = (const float4*)(x + (size_t)row*EMB);
  float4 v0 = xr[ln], v1 = xr[64+ln], v2 = xr[128+ln];
  float s  = v0.x+v0.y+v0.z+v0.w + v1.x+v1.y+v1.z+v1.w + v2.x+v2.y+v2.z+v2.w;
  float s2 = v0.x*v0.x+v0.y*v0.y+v0.z*v0.z+v0.w*v0.w
           + v1.x*v1.x+v1.y*v1.y+v1.z*v1.z+v1.w*v1.w
           + v2.x*v2.x+v2.y*v2.y+v2.z*v2.z+v2.w*v2.w;
  #pragma unroll
  for (int off=1;off<64;off<<=1){ s += __shfl_xor(s,off); s2 += __shfl_xor(s2,off); }
  float mean = s*(1.f/768.f);
  float var  = s2*(1.f/768.f) - mean*mean;
  float rstd = rsqrtf(var + LNEPS);
  uint16_t* orow = out + (size_t)row*EMB;
  float4 vv[3] = {v0,v1,v2};
  #pragma unroll
  for (int i=0;i<3;i++){
    int c = (i*64+ln)*4;
    ushort4 o4;
    o4.x = f2bf((vv[i].x-mean)*rstd*sc[c+0] + sh[c+0]);
    o4.y = f2bf((vv[i].y-mean)*rstd*sc[c+1] + sh[c+1]);
    o4.z = f2bf((vv[i].z-mean)*rstd*sc[c+2] + sh[c+2]);
    o4.w = f2bf((vv[i].w-mean)*rstd*sc[c+3] + sh[c+3]);
    *(ushort4*)(orow + c) = o4;
  }
}

// ---------- GEMM: C[M,N] = A[M,K](bf16) * Bt[N,K](bf16)^T ----------
// Tile TM x 128, double-buffered async LDS staging, one barrier per K-iter.
// MODE 0: store bf16 (z==0 Q scaled by QSCALE; z==2 -> V transposed [b][h][d][s])
// MODE 1: +bias +fp32 residual -> fp32
// MODE 2: +bias, gelu -> bf16
// MODE 3: +bias +fp32 residual -> fp32 (final out)
template<int MODE, int TM>
__global__ __launch_bounds__(256, 4) void gemm_bt(const uint16_t* __restrict__ A,
    const uint16_t* __restrict__ Bt0,
    const float* __restrict__ bias,
    const float* __restrict__ resid,
    void* __restrict__ outp,
    uint16_t* __restrict__ vt_out,
    int N, int K, long bt_zstride, long out_zstride)
{
  constexpr int MI = TM/32;             // m-frags per wave
  __shared__ __align__(16) uint16_t As[2][TM][32];
  __shared__ __align__(16) uint16_t Bs[2][128][32];
  const uint16_t* Bt = Bt0 + (size_t)blockIdx.z * bt_zstride;
  int tid = threadIdx.x;
  int wave = tid>>6, ln = tid&63, lane16 = ln&15, quad = ln>>4;
  int m0 = blockIdx.x*TM, n0 = blockIdx.y*128;
  int wm = (wave>>1)*(MI*16), wn = (wave&1)*64;
  f32x4 zf = {0.f,0.f,0.f,0.f};
  f32x4 acc[MI][4];
  #pragma unroll
  for (int i=0;i<MI;i++)
    #pragma unroll
    for (int j=0;j<4;j++) acc[i][j]=zf;
  int ar = tid>>2;
  int ac = (tid&3)*8;
  const uint16_t* Arow0 = A  + (size_t)(m0+ar)*K    + ac;
  const uint16_t* Arow1 = A  + (size_t)(m0+ar+64)*K + ac;   // TM==128 only
  const uint16_t* Brow0 = Bt + (size_t)(n0+ar)*K    + ac;
  const uint16_t* Brow1 = Bt + (size_t)(n0+ar+64)*K + ac;

  auto stage = [&](int buf, int k0){
    char* lA = (char*)&As[buf][0][0] + wave*1024;
    char* lB = (char*)&Bs[buf][0][0] + wave*1024;
    gload16(Arow0 + k0, lA);
    if (TM==128) gload16(Arow1 + k0, lA + 4096);
    gload16(Brow0 + k0, lB);
    gload16(Brow1 + k0, lB + 4096);
  };

  int niter = K>>5;
  stage(0, 0);
  for (int s=0; s<niter; s++){
    __syncthreads();                    // drains staging of buf s&1
    if (s+1 < niter) stage((s+1)&1, (s+1)<<5);
    int buf = s&1;
    bf16x8 af[MI], bfr[4];
    #pragma unroll
    for (int mi=0;mi<MI;mi++) af[mi]  = *(const bf16x8*)&As[buf][wm+mi*16+lane16][quad*8];
    #pragma unroll
    for (int ni=0;ni<4;ni++)  bfr[ni] = *(const bf16x8*)&Bs[buf][wn+ni*16+lane16][quad*8];
    #pragma unroll
    for (int mi=0;mi<MI;mi++)
      #pragma unroll
      for (int ni=0;ni<4;ni++)
        acc[mi][ni] = __builtin_amdgcn_mfma_f32_16x16x32_bf16(af[mi], bfr[ni], acc[mi][ni], 0,0,0);
  }
  if (MODE==0 && blockIdx.z==2){
    #pragma unroll
    for (int mi=0;mi<MI;mi++){
      int mrow0 = m0 + wm + mi*16 + quad*4;
      int bb = mrow0 >> 11, s = mrow0 & 2047;
      #pragma unroll
      for (int ni=0;ni<4;ni++){
        int ncol = n0 + wn + ni*16 + lane16;
        int hh = ncol >> 6, dd = ncol & 63;
        ushort4 o4 = { f2bf(acc[mi][ni][0]), f2bf(acc[mi][ni][1]),
                       f2bf(acc[mi][ni][2]), f2bf(acc[mi][ni][3]) };
        *(ushort4*)(vt_out + ((size_t)((bb*NHEADS+hh)*HDIM + dd))*SEQ + s) = o4;
      }
    }
    return;
  }
  float oscale = (MODE==0 && blockIdx.z==0) ? QSCALE : 1.0f;
  #pragma unroll
  for (int mi=0;mi<MI;mi++){
    #pragma unroll
    for (int r=0;r<4;r++){
      int mrow = m0 + wm + mi*16 + quad*4 + r;
      #pragma unroll
      for (int ni=0;ni<4;ni++){
        int ncol = n0 + wn + ni*16 + lane16;
        float vv = acc[mi][ni][r];
        size_t idx = (size_t)mrow*N + ncol;
        if (MODE==0){
          ((uint16_t*)outp)[(size_t)blockIdx.z*out_zstride + idx] = f2bf(vv*oscale);
        } else if (MODE==1){
          ((float*)outp)[idx] = vv + bias[ncol] + resid[idx];
        } else if (MODE==2){
          float t = vv + bias[ncol];
          float u = 1.5957691216057308f*(t + 0.044715f*t*t*t);
          ((uint16_t*)outp)[idx] = f2bf(t / (1.f + __expf(-u)));
        } else {
          ((float*)outp)[idx] = vv + bias[ncol] + resid[idx];
        }
      }
    }
  }
}

// ---------- Flash attention v3: LDS-shared K/V, async double-buffer, balanced ----------
// grid (16, NHEADS, BATCH), block 256 (4 waves, 16 q-rows each).
// Block processes 64-q tiles {p, 31-p} sequentially -> 33 kv-steps for every block.
__global__ __launch_bounds__(256, 3) void attn_kernel(const uint16_t* __restrict__ q,
    const uint16_t* __restrict__ k, const uint16_t* __restrict__ vt,
    uint16_t* __restrict__ ctx)
{
  __shared__ __align__(16) uint16_t Ks[2][8][64][8];  // [buf][d-blk][kv][8]
  __shared__ __align__(16) uint16_t Vs[2][8][64][8];  // [buf][kv-blk][d][8]
  const f32x4 zf = {0.f,0.f,0.f,0.f};
  int tid = threadIdx.x;
  int wave = tid>>6, ln = tid&63, l16 = ln&15, quad = ln>>4;
  int b = blockIdx.z, h = blockIdx.y;
  int p = blockIdx.x;
  size_t kgbase = ((size_t)(b*SEQ + ln))*EMB + h*HDIM;       // + kv0*EMB + c*8
  size_t vgbase = ((size_t)((b*NHEADS + h)*HDIM + ln))*SEQ;  // + kv0 + c*8

  f32x4 o[4];
  float m_l, l_l;
  bf16x8 qf0, qf1;
  int q0w, myq;

  auto stage = [&](int buf, int kv0){
    #pragma unroll
    for (int i=0;i<2;i++){
      int c = wave + 4*i;
      gload16(k  + kgbase + (size_t)kv0*EMB + c*8, &Ks[buf][c][0][0]);
      gload16(vt + vgbase + kv0 + c*8,             &Vs[buf][c][0][0]);
    }
  };
  auto init_tile = [&](int tile){
    q0w = tile*64 + wave*16;
    myq = q0w + l16;
    const uint16_t* qrow = q + ((size_t)(b*SEQ + q0w + l16))*EMB + h*HDIM + quad*8;
    qf0 = *(const bf16x8*)(qrow);
    qf1 = *(const bf16x8*)(qrow + 32);
    o[0]=zf; o[1]=zf; o[2]=zf; o[3]=zf;
    m_l = -3.0e38f; l_l = 0.f;
  };
  auto writeout = [&](){
    float inv = 1.0f / l_l;
    uint16_t* crow = ctx + ((size_t)(b*SEQ + q0w + l16))*EMB + h*HDIM + quad*4;
    #pragma unroll
    for (int t=0; t<4; t++){
      ushort4 w4 = { f2bf(o[t][0]*inv), f2bf(o[t][1]*inv),
                     f2bf(o[t][2]*inv), f2bf(o[t][3]*inv) };
      *(ushort4*)(crow + t*16) = w4;
    }
  };
  auto compute = [&](int buf, int kv0, bool masked){
    bf16x8 kf[4][2], vf[2][4];
    #pragma unroll
    for (int f=0; f<4; f++){
      kf[f][0] = *(const bf16x8*)&Ks[buf][quad  ][f*16+l16][0];
      kf[f][1] = *(const bf16x8*)&Ks[buf][quad+4][f*16+l16][0];
    }
    #pragma unroll
    for (int t=0; t<4; t++){
      vf[0][t] = *(const bf16x8*)&Vs[buf][quad  ][t*16+l16][0];
      vf[1][t] = *(const bf16x8*)&Vs[buf][quad+4][t*16+l16][0];
    }
    f32x4 st[4];
    #pragma unroll
    for (int f=0; f<4; f++){
      st[f] = __builtin_amdgcn_mfma_f32_16x16x32_bf16(kf[f][0], qf0, zf, 0,0,0);
      st[f] = __builtin_amdgcn_mfma_f32_16x16x32_bf16(kf[f][1], qf1, st[f], 0,0,0);
    }
    if (masked){
      #pragma unroll
      for (int f=0; f<4; f++){
        int kvf = kv0 + f*16 + quad*4;
        #pragma unroll
        for (int r=0; r<4; r++)
          if (kvf + r > myq) st[f][r] = -1e30f;
      }
    }
    float cmax = -1e30f;
    #pragma unroll
    for (int f=0; f<4; f++)
      #pragma unroll
      for (int r=0; r<4; r++) cmax = fmaxf(cmax, st[f][r]);
    cmax = fmaxf(cmax, __shfl_xor(cmax,16));
    cmax = fmaxf(cmax, __shfl_xor(cmax,32));
    float mn = fmaxf(m_l, cmax);
    float alpha = __builtin_amdgcn_exp2f(m_l - mn);
    float rs = 0.f;
    #pragma unroll
    for (int f=0; f<4; f++)
      #pragma unroll
      for (int r=0; r<4; r++){
        st[f][r] = __builtin_amdgcn_exp2f(st[f][r] - mn);
        rs += st[f][r];
      }
    rs += __shfl_xor(rs,16); rs += __shfl_xor(rs,32);
    l_l = l_l*alpha + rs; m_l = mn;
    #pragma unroll
    for (int t=0; t<4; t++)
      #pragma unroll
      for (int r=0; r<4; r++) o[t][r] *= alpha;
    uint32_t dw[4][2];
    #pragma unroll
    for (int f=0; f<4; f++){
      dw[f][0] = pk_rhu(st[f][0], st[f][1]);
      dw[f][1] = pk_rhu(st[f][2], st[f][3]);
    }
    union { uint32_t u[4]; bf16x8 v; } pb[2];
    #pragma unroll
    for (int g=0; g<2; g++)
      #pragma unroll
      for (int j=0; j<4; j++){
        int src = 16*(2*(quad&1) + (j>>1)) + l16;
        uint32_t lo = (uint32_t)__shfl((int)dw[2*g  ][j&1], src, 64);
        uint32_t hi = (uint32_t)__shfl((int)dw[2*g+1][j&1], src, 64);
        pb[g].u[j] = (quad>>1) ? hi : lo;
      }
    #pragma unroll
    for (int t=0; t<4; t++){
      o[t] = __builtin_amdgcn_mfma_f32_16x16x32_bf16(vf[0][t], pb[0].v, o[t], 0,0,0);
      o[t] = __builtin_amdgcn_mfma_f32_16x16x32_bf16(vf[1][t], pb[1].v, o[t], 0,0,0);
    }
  };

  int n0 = p + 1, ntot = 33;
  init_tile(p);
  stage(0, 0);
  for (int s=0; s<ntot; s++){
    int sl = (s < n0) ? s : s - n0;
    int kv0 = sl*64;
    __syncthreads();                 // drains staging of buf s&1
    if (s+1 < ntot){
      int sn = s+1;
      int snl = (sn < n0) ? sn : sn - n0;
      stage(sn&1, snl*64);           // in flight during compute below
    }
    if (s == n0){ writeout(); init_tile(31 - p); }
    bool masked = (s == n0-1) || (s == ntot-1);
    compute(s&1, kv0, masked);
  }
  writeout();
}

extern "C" void kernel_launch(void* const* d_in, const int* in_sizes, int n_in,
                              void* d_out, int out_size, void* d_ws, size_t ws_size,
                              hipStream_t stream) {
  const float* x     = (const float*)d_in[0];
  const float* ln1_s = (const float*)d_in[1];
  const float* ln1_b = (const float*)d_in[2];
  const float* wq    = (const float*)d_in[3];
  const float* wk    = (const float*)d_in[4];
  const float* wv    = (const float*)d_in[5];
  const float* wo    = (const float*)d_in[6];
  const float* bo    = (const float*)d_in[7];
  const float* ln2_s = (const float*)d_in[8];
  const float* ln2_b = (const float*)d_in[9];
  const float* w1    = (const float*)d_in[10];
  const float* b1    = (const float*)d_in[11];
  const float* w2    = (const float*)d_in[12];
  const float* b2    = (const float*)d_in[13];

  uint16_t* wqkv_t = (uint16_t*)d_ws;                 // 3 x [768][768]
  uint16_t* wo_t   = wqkv_t + 3*EMB*EMB;              // [768][768]
  uint16_t* w1_t   = wo_t   + EMB*EMB;                // [3072][768]
  uint16_t* w2_t   = w1_t   + (size_t)FFDIM*EMB;      // [768][3072]
  uint16_t* xn     = w2_t   + (size_t)EMB*FFDIM;      // [8192][768]
  uint16_t* qkv    = xn     + (size_t)NTOK*EMB;       // q,k normal; v slot unused
  uint16_t* ctx    = qkv    + (size_t)3*NTOK*EMB;     // [8192][768]
  uint16_t* hff    = qkv;                             // [8192][3072] overlays qkv+ctx
  float*    x1     = (float*)(ctx + (size_t)NTOK*EMB);// [8192][768] fp32
  uint16_t* vt     = (uint16_t*)(x1 + (size_t)NTOK*EMB); // [4][12][64][2048] V^T

  TPtrs tp;
  tp.src[0]=wq; tp.src[1]=wk; tp.src[2]=wv; tp.src[3]=wo; tp.src[4]=w1; tp.src[5]=w2;
  tp.dst[0]=wqkv_t; tp.dst[1]=wqkv_t+EMB*EMB; tp.dst[2]=wqkv_t+2*EMB*EMB;
  tp.dst[3]=wo_t; tp.dst[4]=w1_t; tp.dst[5]=w2_t;
  transpose_all<<<6912, dim3(32,8), 0, stream>>>(tp);

  ln_kernel<<<NTOK/4, 256, 0, stream>>>(x, ln1_s, ln1_b, xn);
  gemm_bt<0,128><<<dim3(NTOK/128, EMB/128, 3), 256, 0, stream>>>(
      xn, wqkv_t, nullptr, nullptr, qkv, vt, EMB, EMB,
      (long)EMB*EMB, (long)NTOK*EMB);
  attn_kernel<<<dim3(16, NHEADS, BATCH), 256, 0, stream>>>(
      qkv, qkv + (size_t)NTOK*EMB, vt, ctx);
  // proj: TM=64 -> grid 128x6 = 768 blocks (3/CU)
  gemm_bt<1,64><<<dim3(NTOK/64, EMB/128, 1), 256, 0, stream>>>(
      ctx, wo_t, bo, x, x1, nullptr, EMB, EMB, 0, 0);
  ln_kernel<<<NTOK/4, 256, 0, stream>>>(x1, ln2_s, ln2_b, xn);
  gemm_bt<2,128><<<dim3(NTOK/128, FFDIM/128, 1), 256, 0, stream>>>(
      xn, w1_t, b1, nullptr, hff, nullptr, FFDIM, EMB, 0, 0);
  // FFN2: TM=64 -> grid 128x6 = 768 blocks (3/CU)
  gemm_bt<3,64><<<dim3(NTOK/64, EMB/128, 1), 256, 0, stream>>>(
      hff, w2_t, b2, x1, d_out, nullptr, EMB, FFDIM, 0, 0);
}

// Round 7
// 377.877 us; speedup vs baseline: 1.3846x; 1.0079x over previous
//
#include <hip/hip_runtime.h>
#include <stdint.h>

#define EMB 768
#define SEQ 2048
#define BATCH 4
#define NHEADS 12
#define HDIM 64
#define FFDIM 3072
#define NTOK (BATCH*SEQ)
#define LNEPS 1e-5f
#define QSCALE 0.1803368801111137f  /* 0.125 * log2(e) */

typedef __attribute__((ext_vector_type(8))) short bf16x8;
typedef __attribute__((ext_vector_type(4))) float f32x4;

__device__ __forceinline__ uint16_t f2bf(float f){
  union { float f; uint32_t u; } v; v.f = f;
  uint32_t r = v.u + 0x7fffu + ((v.u >> 16) & 1u);
  return (uint16_t)(r >> 16);
}
// pack two floats to bf16 pair, round-half-up (add 0x8000, take hi16) via v_perm
__device__ __forceinline__ uint32_t pk_rhu(float lo, float hi){
  union { float f; uint32_t u; } a, b; a.f = lo; b.f = hi;
  return __builtin_amdgcn_perm(b.u + 0x8000u, a.u + 0x8000u, 0x07060302u);
}

// async global->LDS, 16B per lane. LDS dest = wave-uniform base + lane*16.
typedef __attribute__((address_space(3))) uint32_t lds32_t;
typedef __attribute__((address_space(1))) const uint32_t glb32_t;
__device__ __forceinline__ void gload16(const void* g, void* l){
  __builtin_amdgcn_global_load_lds((glb32_t*)(uintptr_t)g,
                                   (lds32_t*)(uintptr_t)l, 16, 0, 0);
}

// ---------- merged fp32 [K,N] -> bf16 [N,K] weight convert+transpose ----------
struct TPtrs { const float* src[6]; uint16_t* dst[6]; };
__global__ __launch_bounds__(256) void transpose_all(TPtrs tp){
  int idx = blockIdx.x;
  int which, bx, by, K, N;
  if (idx < 2304){ which = idx/576; int l = idx - which*576; bx = l%24; by = l/24; K = 768;  N = 768;  }
  else if (idx < 4608){ which = 4; int l = idx-2304; bx = l%96; by = l/96; K = 768;  N = 3072; }
  else { which = 5; int l = idx-4608; bx = l%24; by = l/24; K = 3072; N = 768;  }
  const float* w = tp.src[which];
  uint16_t* wt   = tp.dst[which];
  __shared__ uint16_t tile[32][33];
  int n0 = bx*32, k0 = by*32;
  #pragma unroll
  for (int i=0;i<4;i++){
    int k = threadIdx.y + i*8;
    tile[k][threadIdx.x] = f2bf(w[(size_t)(k0+k)*N + n0 + threadIdx.x]);
  }
  __syncthreads();
  #pragma unroll
  for (int i=0;i<4;i++){
    int n = threadIdx.y + i*8;
    wt[(size_t)(n0+n)*K + k0 + threadIdx.x] = tile[threadIdx.x][n];
  }
}

// ---------- LayerNorm: fp32 in -> bf16 out, one wave per row ----------
__global__ __launch_bounds__(256) void ln_kernel(const float* __restrict__ x,
    const float* __restrict__ sc, const float* __restrict__ sh,
    uint16_t* __restrict__ out)
{
  int row = blockIdx.x*4 + (threadIdx.x>>6);
  int ln = threadIdx.x & 63;
  const float4* xr = (const float4*)(x + (size_t)row*EMB);
  float4 v0 = xr[ln], v1 = xr[64+ln], v2 = xr[128+ln];
  float s  = v0.x+v0.y+v0.z+v0.w + v1.x+v1.y+v1.z+v1.w + v2.x+v2.y+v2.z+v2.w;
  float s2 = v0.x*v0.x+v0.y*v0.y+v0.z*v0.z+v0.w*v0.w
           + v1.x*v1.x+v1.y*v1.y+v1.z*v1.z+v1.w*v1.w
           + v2.x*v2.x+v2.y*v2.y+v2.z*v2.z+v2.w*v2.w;
  #pragma unroll
  for (int off=1;off<64;off<<=1){ s += __shfl_xor(s,off); s2 += __shfl_xor(s2,off); }
  float mean = s*(1.f/768.f);
  float var  = s2*(1.f/768.f) - mean*mean;
  float rstd = rsqrtf(var + LNEPS);
  uint16_t* orow = out + (size_t)row*EMB;
  float4 vv[3] = {v0,v1,v2};
  #pragma unroll
  for (int i=0;i<3;i++){
    int c = (i*64+ln)*4;
    ushort4 o4;
    o4.x = f2bf((vv[i].x-mean)*rstd*sc[c+0] + sh[c+0]);
    o4.y = f2bf((vv[i].y-mean)*rstd*sc[c+1] + sh[c+1]);
    o4.z = f2bf((vv[i].z-mean)*rstd*sc[c+2] + sh[c+2]);
    o4.w = f2bf((vv[i].w-mean)*rstd*sc[c+3] + sh[c+3]);
    *(ushort4*)(orow + c) = o4;
  }
}

// ---------- GEMM: C[M,N] = A[M,K](bf16) * Bt[N,K](bf16)^T ----------
// Tile TM x 128, double-buffered async LDS staging, one barrier per K-iter.
// MODE 0: store bf16 (z==0 Q scaled by QSCALE; z==2 -> V transposed [b][h][d][s])
// MODE 1: +bias +fp32 residual -> fp32
// MODE 2: +bias, gelu -> bf16
// MODE 3: +bias +fp32 residual -> fp32 (final out)
template<int MODE, int TM>
__global__ __launch_bounds__(256, 4) void gemm_bt(const uint16_t* __restrict__ A,
    const uint16_t* __restrict__ Bt0,
    const float* __restrict__ bias,
    const float* __restrict__ resid,
    void* __restrict__ outp,
    uint16_t* __restrict__ vt_out,
    int N, int K, long bt_zstride, long out_zstride)
{
  constexpr int MI = TM/32;             // m-frags per wave
  __shared__ __align__(16) uint16_t As[2][TM][32];
  __shared__ __align__(16) uint16_t Bs[2][128][32];
  const uint16_t* Bt = Bt0 + (size_t)blockIdx.z * bt_zstride;
  int tid = threadIdx.x;
  int wave = tid>>6, ln = tid&63, lane16 = ln&15, quad = ln>>4;
  int m0 = blockIdx.x*TM, n0 = blockIdx.y*128;
  int wm = (wave>>1)*(MI*16), wn = (wave&1)*64;
  f32x4 zf = {0.f,0.f,0.f,0.f};
  f32x4 acc[MI][4];
  #pragma unroll
  for (int i=0;i<MI;i++)
    #pragma unroll
    for (int j=0;j<4;j++) acc[i][j]=zf;
  int ar = tid>>2;
  int ac = (tid&3)*8;
  const uint16_t* Arow0 = A  + (size_t)(m0+ar)*K    + ac;
  const uint16_t* Arow1 = A  + (size_t)(m0+ar+64)*K + ac;   // TM==128 only
  const uint16_t* Brow0 = Bt + (size_t)(n0+ar)*K    + ac;
  const uint16_t* Brow1 = Bt + (size_t)(n0+ar+64)*K + ac;

  auto stage = [&](int buf, int k0){
    char* lA = (char*)&As[buf][0][0] + wave*1024;
    char* lB = (char*)&Bs[buf][0][0] + wave*1024;
    gload16(Arow0 + k0, lA);
    if (TM==128) gload16(Arow1 + k0, lA + 4096);
    gload16(Brow0 + k0, lB);
    gload16(Brow1 + k0, lB + 4096);
  };

  int niter = K>>5;
  stage(0, 0);
  for (int s=0; s<niter; s++){
    __syncthreads();                    // drains staging of buf s&1
    if (s+1 < niter) stage((s+1)&1, (s+1)<<5);
    int buf = s&1;
    bf16x8 af[MI], bfr[4];
    #pragma unroll
    for (int mi=0;mi<MI;mi++) af[mi]  = *(const bf16x8*)&As[buf][wm+mi*16+lane16][quad*8];
    #pragma unroll
    for (int ni=0;ni<4;ni++)  bfr[ni] = *(const bf16x8*)&Bs[buf][wn+ni*16+lane16][quad*8];
    #pragma unroll
    for (int mi=0;mi<MI;mi++)
      #pragma unroll
      for (int ni=0;ni<4;ni++)
        acc[mi][ni] = __builtin_amdgcn_mfma_f32_16x16x32_bf16(af[mi], bfr[ni], acc[mi][ni], 0,0,0);
  }
  if (MODE==0 && blockIdx.z==2){
    #pragma unroll
    for (int mi=0;mi<MI;mi++){
      int mrow0 = m0 + wm + mi*16 + quad*4;
      int bb = mrow0 >> 11, s = mrow0 & 2047;
      #pragma unroll
      for (int ni=0;ni<4;ni++){
        int ncol = n0 + wn + ni*16 + lane16;
        int hh = ncol >> 6, dd = ncol & 63;
        ushort4 o4 = { f2bf(acc[mi][ni][0]), f2bf(acc[mi][ni][1]),
                       f2bf(acc[mi][ni][2]), f2bf(acc[mi][ni][3]) };
        *(ushort4*)(vt_out + ((size_t)((bb*NHEADS+hh)*HDIM + dd))*SEQ + s) = o4;
      }
    }
    return;
  }
  float oscale = (MODE==0 && blockIdx.z==0) ? QSCALE : 1.0f;
  #pragma unroll
  for (int mi=0;mi<MI;mi++){
    #pragma unroll
    for (int r=0;r<4;r++){
      int mrow = m0 + wm + mi*16 + quad*4 + r;
      #pragma unroll
      for (int ni=0;ni<4;ni++){
        int ncol = n0 + wn + ni*16 + lane16;
        float vv = acc[mi][ni][r];
        size_t idx = (size_t)mrow*N + ncol;
        if (MODE==0){
          ((uint16_t*)outp)[(size_t)blockIdx.z*out_zstride + idx] = f2bf(vv*oscale);
        } else if (MODE==1){
          ((float*)outp)[idx] = vv + bias[ncol] + resid[idx];
        } else if (MODE==2){
          float t = vv + bias[ncol];
          float u = 1.5957691216057308f*(t + 0.044715f*t*t*t);
          ((uint16_t*)outp)[idx] = f2bf(t / (1.f + __expf(-u)));
        } else {
          ((float*)outp)[idx] = vv + bias[ncol] + resid[idx];
        }
      }
    }
  }
}

// ---------- Flash attention v4: XCD-clustered grid, LDS dbuf K/V ----------
// 1D grid of 768 blocks; decode so all 16 q-pair-blocks of one (b,h) land on
// ONE XCD (dispatch round-robins flat id % 8): per-XCD K/V working set =
// 6 pairs x 512 KB = 3 MB < 4 MB L2 -> each pair's K/V fetched from HBM once.
// Block processes 64-q tiles {p, 31-p} sequentially -> 33 kv-steps every block.
__global__ __launch_bounds__(256, 3) void attn_kernel(const uint16_t* __restrict__ q,
    const uint16_t* __restrict__ k, const uint16_t* __restrict__ vt,
    uint16_t* __restrict__ ctx)
{
  __shared__ __align__(16) uint16_t Ks[2][8][64][8];  // [buf][d-blk][kv][8]
  __shared__ __align__(16) uint16_t Vs[2][8][64][8];  // [buf][kv-blk][d][8]
  const f32x4 zf = {0.f,0.f,0.f,0.f};
  int tid = threadIdx.x;
  int wave = tid>>6, ln = tid&63, l16 = ln&15, quad = ln>>4;
  // XCD-clustered decode
  int id  = blockIdx.x;        // 0..767
  int xcd = id & 7;
  int s_  = id >> 3;           // 0..95
  int p   = s_ & 15;           // q-pair index 0..15
  int g   = xcd*6 + (s_ >> 4); // (b,h) group 0..47, one XCD per group
  int h   = g % NHEADS, b = g / NHEADS;
  size_t kgbase = ((size_t)(b*SEQ + ln))*EMB + h*HDIM;       // + kv0*EMB + c*8
  size_t vgbase = ((size_t)((b*NHEADS + h)*HDIM + ln))*SEQ;  // + kv0 + c*8

  f32x4 o[4];
  float m_l, l_l;
  bf16x8 qf0, qf1;
  int q0w, myq;

  auto stage = [&](int buf, int kv0){
    #pragma unroll
    for (int i=0;i<2;i++){
      int c = wave + 4*i;
      gload16(k  + kgbase + (size_t)kv0*EMB + c*8, &Ks[buf][c][0][0]);
      gload16(vt + vgbase + kv0 + c*8,             &Vs[buf][c][0][0]);
    }
  };
  auto init_tile = [&](int tile){
    q0w = tile*64 + wave*16;
    myq = q0w + l16;
    const uint16_t* qrow = q + ((size_t)(b*SEQ + q0w + l16))*EMB + h*HDIM + quad*8;
    qf0 = *(const bf16x8*)(qrow);
    qf1 = *(const bf16x8*)(qrow + 32);
    o[0]=zf; o[1]=zf; o[2]=zf; o[3]=zf;
    m_l = -3.0e38f; l_l = 0.f;
  };
  auto writeout = [&](){
    float inv = 1.0f / l_l;
    uint16_t* crow = ctx + ((size_t)(b*SEQ + q0w + l16))*EMB + h*HDIM + quad*4;
    #pragma unroll
    for (int t=0; t<4; t++){
      ushort4 w4 = { f2bf(o[t][0]*inv), f2bf(o[t][1]*inv),
                     f2bf(o[t][2]*inv), f2bf(o[t][3]*inv) };
      *(ushort4*)(crow + t*16) = w4;
    }
  };
  auto compute = [&](int buf, int kv0, bool masked){
    bf16x8 kf[4][2], vf[2][4];
    #pragma unroll
    for (int f=0; f<4; f++){
      kf[f][0] = *(const bf16x8*)&Ks[buf][quad  ][f*16+l16][0];
      kf[f][1] = *(const bf16x8*)&Ks[buf][quad+4][f*16+l16][0];
    }
    #pragma unroll
    for (int t=0; t<4; t++){
      vf[0][t] = *(const bf16x8*)&Vs[buf][quad  ][t*16+l16][0];
      vf[1][t] = *(const bf16x8*)&Vs[buf][quad+4][t*16+l16][0];
    }
    f32x4 st[4];
    #pragma unroll
    for (int f=0; f<4; f++){
      st[f] = __builtin_amdgcn_mfma_f32_16x16x32_bf16(kf[f][0], qf0, zf, 0,0,0);
      st[f] = __builtin_amdgcn_mfma_f32_16x16x32_bf16(kf[f][1], qf1, st[f], 0,0,0);
    }
    if (masked){
      #pragma unroll
      for (int f=0; f<4; f++){
        int kvf = kv0 + f*16 + quad*4;
        #pragma unroll
        for (int r=0; r<4; r++)
          if (kvf + r > myq) st[f][r] = -1e30f;
      }
    }
    float cmax = -1e30f;
    #pragma unroll
    for (int f=0; f<4; f++)
      #pragma unroll
      for (int r=0; r<4; r++) cmax = fmaxf(cmax, st[f][r]);
    cmax = fmaxf(cmax, __shfl_xor(cmax,16));
    cmax = fmaxf(cmax, __shfl_xor(cmax,32));
    float mn = fmaxf(m_l, cmax);
    float alpha = __builtin_amdgcn_exp2f(m_l - mn);
    float rs = 0.f;
    #pragma unroll
    for (int f=0; f<4; f++)
      #pragma unroll
      for (int r=0; r<4; r++){
        st[f][r] = __builtin_amdgcn_exp2f(st[f][r] - mn);
        rs += st[f][r];
      }
    rs += __shfl_xor(rs,16); rs += __shfl_xor(rs,32);
    l_l = l_l*alpha + rs; m_l = mn;
    #pragma unroll
    for (int t=0; t<4; t++)
      #pragma unroll
      for (int r=0; r<4; r++) o[t][r] *= alpha;
    uint32_t dw[4][2];
    #pragma unroll
    for (int f=0; f<4; f++){
      dw[f][0] = pk_rhu(st[f][0], st[f][1]);
      dw[f][1] = pk_rhu(st[f][2], st[f][3]);
    }
    union { uint32_t u[4]; bf16x8 v; } pb[2];
    #pragma unroll
    for (int g2=0; g2<2; g2++)
      #pragma unroll
      for (int j=0; j<4; j++){
        int src = 16*(2*(quad&1) + (j>>1)) + l16;
        uint32_t lo = (uint32_t)__shfl((int)dw[2*g2  ][j&1], src, 64);
        uint32_t hi = (uint32_t)__shfl((int)dw[2*g2+1][j&1], src, 64);
        pb[g2].u[j] = (quad>>1) ? hi : lo;
      }
    #pragma unroll
    for (int t=0; t<4; t++){
      o[t] = __builtin_amdgcn_mfma_f32_16x16x32_bf16(vf[0][t], pb[0].v, o[t], 0,0,0);
      o[t] = __builtin_amdgcn_mfma_f32_16x16x32_bf16(vf[1][t], pb[1].v, o[t], 0,0,0);
    }
  };

  int n0 = p + 1, ntot = 33;
  init_tile(p);
  stage(0, 0);
  for (int s=0; s<ntot; s++){
    int sl = (s < n0) ? s : s - n0;
    int kv0 = sl*64;
    __syncthreads();                 // drains staging of buf s&1
    if (s+1 < ntot){
      int sn = s+1;
      int snl = (sn < n0) ? sn : sn - n0;
      stage(sn&1, snl*64);           // in flight during compute below
    }
    if (s == n0){ writeout(); init_tile(31 - p); }
    bool masked = (s == n0-1) || (s == ntot-1);
    compute(s&1, kv0, masked);
  }
  writeout();
}

extern "C" void kernel_launch(void* const* d_in, const int* in_sizes, int n_in,
                              void* d_out, int out_size, void* d_ws, size_t ws_size,
                              hipStream_t stream) {
  const float* x     = (const float*)d_in[0];
  const float* ln1_s = (const float*)d_in[1];
  const float* ln1_b = (const float*)d_in[2];
  const float* wq    = (const float*)d_in[3];
  const float* wk    = (const float*)d_in[4];
  const float* wv    = (const float*)d_in[5];
  const float* wo    = (const float*)d_in[6];
  const float* bo    = (const float*)d_in[7];
  const float* ln2_s = (const float*)d_in[8];
  const float* ln2_b = (const float*)d_in[9];
  const float* w1    = (const float*)d_in[10];
  const float* b1    = (const float*)d_in[11];
  const float* w2    = (const float*)d_in[12];
  const float* b2    = (const float*)d_in[13];

  uint16_t* wqkv_t = (uint16_t*)d_ws;                 // 3 x [768][768]
  uint16_t* wo_t   = wqkv_t + 3*EMB*EMB;              // [768][768]
  uint16_t* w1_t   = wo_t   + EMB*EMB;                // [3072][768]
  uint16_t* w2_t   = w1_t   + (size_t)FFDIM*EMB;      // [768][3072]
  uint16_t* xn     = w2_t   + (size_t)EMB*FFDIM;      // [8192][768]
  uint16_t* qkv    = xn     + (size_t)NTOK*EMB;       // q,k normal; v slot unused
  uint16_t* ctx    = qkv    + (size_t)3*NTOK*EMB;     // [8192][768]
  uint16_t* hff    = qkv;                             // [8192][3072] overlays qkv+ctx
  float*    x1     = (float*)(ctx + (size_t)NTOK*EMB);// [8192][768] fp32
  uint16_t* vt     = (uint16_t*)(x1 + (size_t)NTOK*EMB); // [4][12][64][2048] V^T

  TPtrs tp;
  tp.src[0]=wq; tp.src[1]=wk; tp.src[2]=wv; tp.src[3]=wo; tp.src[4]=w1; tp.src[5]=w2;
  tp.dst[0]=wqkv_t; tp.dst[1]=wqkv_t+EMB*EMB; tp.dst[2]=wqkv_t+2*EMB*EMB;
  tp.dst[3]=wo_t; tp.dst[4]=w1_t; tp.dst[5]=w2_t;
  transpose_all<<<6912, dim3(32,8), 0, stream>>>(tp);

  ln_kernel<<<NTOK/4, 256, 0, stream>>>(x, ln1_s, ln1_b, xn);
  gemm_bt<0,128><<<dim3(NTOK/128, EMB/128, 3), 256, 0, stream>>>(
      xn, wqkv_t, nullptr, nullptr, qkv, vt, EMB, EMB,
      (long)EMB*EMB, (long)NTOK*EMB);
  attn_kernel<<<768, 256, 0, stream>>>(
      qkv, qkv + (size_t)NTOK*EMB, vt, ctx);
  // proj: TM=64 -> grid 128x6 = 768 blocks (3/CU)
  gemm_bt<1,64><<<dim3(NTOK/64, EMB/128, 1), 256, 0, stream>>>(
      ctx, wo_t, bo, x, x1, nullptr, EMB, EMB, 0, 0);
  ln_kernel<<<NTOK/4, 256, 0, stream>>>(x1, ln2_s, ln2_b, xn);
  gemm_bt<2,128><<<dim3(NTOK/128, FFDIM/128, 1), 256, 0, stream>>>(
      xn, w1_t, b1, nullptr, hff, nullptr, FFDIM, EMB, 0, 0);
  // FFN2: TM=64 -> grid 128x6 = 768 blocks (3/CU)
  gemm_bt<3,64><<<dim3(NTOK/64, EMB/128, 1), 256, 0, stream>>>(
      hff, w2_t, b2, x1, d_out, nullptr, EMB, FFDIM, 0, 0);
}